// Round 7
// baseline (393.169 us; speedup 1.0000x reference)
//
#include <hip/hip_runtime.h>
#include <hip/hip_bf16.h>

typedef __bf16 bf16_t;
typedef __bf16 bf16x8 __attribute__((ext_vector_type(8)));
typedef float f32x4 __attribute__((ext_vector_type(4)));

#define DEVI static __device__ __forceinline__

static constexpr int E_ = 8, C_ = 1024, DIN = 4096, DOUT = 1024, TOK = 4096;
static constexpr int EC = E_ * C_;             // 8192
static constexpr int BK = 64;
static constexpr int NT = 512;                 // 8 waves / block, 64x64 per wave

// ---- workspace layout (bytes) ----  (104 MB total, same as proven rounds)
static constexpr size_t WS_WT   = 0;                                       // [E][DOUT][DIN] bf16 (swizzled)
static constexpr size_t WS_RWT  = WS_WT   + (size_t)E_ * DOUT * DIN * 2;   // [DOUT][DIN] bf16 (swizzled)
static constexpr size_t WS_EOT0 = WS_RWT  + (size_t)DOUT * DIN * 2;        // [DOUT][EC] bf16 half0 -> merged+swizzled
static constexpr size_t WS_EOT1 = WS_EOT0 + (size_t)DOUT * EC * 2;         // [DOUT][EC] bf16 half1 (plain)

// XOR-swizzle within each 64-element K-group: chunk(col>>3 & 7) ^= row&7.
// Pre-applied to the GLOBAL layout of bf16 ws operands (rule 21).
DEVI int swz(int row, int col) {
    return (col & ~63) | ((col & 56) ^ ((row & 7) << 3)) | (col & 7);
}

// ============ prepass: transpose + cast weights to bf16 [out][in], swizzled ============
__global__ __launch_bounds__(256)
void transpose_cast_kernel(const float* __restrict__ expert_w,
                           const float* __restrict__ residual_w,
                           bf16_t* __restrict__ wt, bf16_t* __restrict__ rwt)
{
    __shared__ float tile[32][33];
    const int z = blockIdx.z;
    const float* src;
    bf16_t* dst;
    if (z < 8) { src = expert_w + (size_t)z * DIN * DOUT; dst = wt + (size_t)z * DOUT * DIN; }
    else       { src = residual_w;                         dst = rwt; }
    const int c0 = blockIdx.x * 32;   // col in src  (DOUT dim -> dst row)
    const int r0 = blockIdx.y * 32;   // row in src  (DIN dim  -> dst col/K)
    const int tx = threadIdx.x, ty = threadIdx.y;  // 32 x 8
#pragma unroll
    for (int k = 0; k < 4; ++k)
        tile[ty + 8 * k][tx] = src[(size_t)(r0 + ty + 8 * k) * DOUT + c0 + tx];
    __syncthreads();
#pragma unroll
    for (int k = 0; k < 4; ++k) {
        const int row = c0 + ty + 8 * k;      // DOUT
        const int col = r0 + tx;              // DIN (K)
        dst[(size_t)row * DIN + swz(row, col)] = (bf16_t)tile[tx][ty + 8 * k];
    }
}

// ============ LDS staging (8 waves) ============
// bf16 ws operand, pre-swizzled source: linear DMA copy
template<int NELEM>
DEVI void stage_bf16(bf16_t* lds, const bf16_t* g, int ld, int tid)
{
    constexpr int PER_WAVE = NELEM / 8;
    constexpr int NI = PER_WAVE / 512;
    const int w = tid >> 6, l = tid & 63;
#pragma unroll
    for (int i = 0; i < NI; ++i) {
        const int eoff = w * PER_WAVE + i * 512 + l * 8;
        const int r = eoff >> 6, c = eoff & 63;
        const bf16_t* gp = g + (size_t)r * ld + c;
        bf16_t* lp = lds + w * PER_WAVE + i * 512;   // wave-uniform base; HW adds lane*16B
        __builtin_amdgcn_global_load_lds(
            (const __attribute__((address_space(1))) void*)gp,
            (__attribute__((address_space(3))) void*)lp, 16, 0, 0);
    }
}

// f32 operand: reg-stage + cvt + swizzled ds_write (R3-proven single pass)
template<int NELEM>
DEVI void stage_f32(bf16_t* lds, const float* __restrict__ g, int ld, int tid)
{
    constexpr int NI = NELEM / (NT * 8);
#pragma unroll
    for (int i = 0; i < NI; ++i) {
        const int eoff = i * NT * 8 + tid * 8;
        const int r = eoff >> 6, c = eoff & 63;        // c is 8-aligned
        const float* gp = g + (size_t)r * ld + c;
        f32x4 v0 = *(const f32x4*)(gp);
        f32x4 v1 = *(const f32x4*)(gp + 4);
        bf16x8 h;
        h[0] = (bf16_t)v0[0]; h[1] = (bf16_t)v0[1];
        h[2] = (bf16_t)v0[2]; h[3] = (bf16_t)v0[3];
        h[4] = (bf16_t)v1[0]; h[5] = (bf16_t)v1[1];
        h[6] = (bf16_t)v1[2]; h[7] = (bf16_t)v1[3];
        const int cs = (c & 56) ^ ((r & 7) << 3);
        *(bf16x8*)(lds + r * 64 + cs) = h;
    }
}

// ============ expert GEMM (split-K x2, 128x256 tile, 64x64 waves) ============
// EOTh[m][e*C+c] = sum_{d in half h} WT_e[m][d] * front_e[c][d]  (+bias in h0)
__global__ __launch_bounds__(NT, 4)
void expert_gemm(const bf16_t* __restrict__ WT, const float* __restrict__ inputs,
                 bf16_t* __restrict__ EOT0, bf16_t* __restrict__ EOT1,
                 const float* __restrict__ expert_b)
{
    __shared__ bf16_t As[128 * BK];   // WT rows (DOUT)
    __shared__ bf16_t Bs[256 * BK];   // front rows (C)
    const int tid = threadIdx.x;

    // T1: bijective XCD-chunked swizzle. nwg=512 -> chunk of 64 = one expert.
    int id = blockIdx.x;
    id = (id & 7) * 64 + (id >> 3);
    const int bx = id & 3, by = (id >> 2) & 7, zz = id >> 5;
    const int e = zz >> 1, h = zz & 1;

    const int brow = by * 128;   // DOUT
    const int bcol = bx * 256;   // C
    const int kbeg = h * (DIN / 2);
    const bf16_t* A = WT + (size_t)e * DOUT * DIN + (size_t)brow * DIN;
    const float*  B = inputs + (size_t)e * C_ * DIN + (size_t)bcol * DIN;

    const int w = tid >> 6, l = tid & 63;
    const int wr = (w >> 2) * 64, wc = (w & 3) * 64;   // 2x4 waves of 64x64
    const int lr = l & 15, lk = l >> 4, sw = (l & 7) << 3;

    f32x4 acc[4][4] = {};

    for (int k0 = kbeg; k0 < kbeg + DIN / 2; k0 += BK) {
        stage_bf16<128 * BK>(As, A + k0, DIN, tid);
        stage_f32<256 * BK>(Bs, B + k0, DIN, tid);
        __syncthreads();
#pragma unroll
        for (int kk = 0; kk < 2; ++kk) {
            const int cs = (kk * 32 + lk * 8) ^ sw;
            bf16x8 a[4], b[4];
#pragma unroll
            for (int m = 0; m < 4; ++m)
                a[m] = *(const bf16x8*)(&As[(wr + m * 16 + lr) * BK + cs]);
#pragma unroll
            for (int n = 0; n < 4; ++n)
                b[n] = *(const bf16x8*)(&Bs[(wc + n * 16 + lr) * BK + cs]);
#pragma unroll
            for (int m = 0; m < 4; ++m)
#pragma unroll
                for (int n = 0; n < 4; ++n)
                    acc[m][n] = __builtin_amdgcn_mfma_f32_16x16x32_bf16(a[m], b[n], acc[m][n], 0, 0, 0);
        }
        __syncthreads();
    }

    bf16_t* EOT = h ? EOT1 : EOT0;
    // C/D frag: col=lane&15, row=(lane>>4)*4+j ; plain row-major write
#pragma unroll
    for (int m = 0; m < 4; ++m) {
#pragma unroll
        for (int n = 0; n < 4; ++n) {
            const int col = bcol + wc + n * 16 + lr;     // C index
#pragma unroll
            for (int j = 0; j < 4; ++j) {
                const int row = brow + wr + m * 16 + lk * 4 + j;   // DOUT index
                float v = acc[m][n][j];
                if (h == 0) v += expert_b[e * DOUT + row];
                EOT[(size_t)row * EC + e * C_ + col] = (bf16_t)v;
            }
        }
    }
}

// ============ merge halves + swizzle, IN PLACE over EOT0 ============
// Each thread owns one full 64-element K-group -> read both halves to regs,
// sum, write back swizzled within its own 128B region (no cross-thread hazard).
__global__ __launch_bounds__(256)
void merge_swz_kernel(bf16_t* __restrict__ EOT0, const bf16_t* __restrict__ EOT1)
{
    const int gid = blockIdx.x * 256 + threadIdx.x;   // DOUT * EC/64 = 131072
    const int row = gid >> 7;
    const int g   = (gid & 127) * 64;
    bf16_t* p0 = EOT0 + (size_t)row * EC + g;
    const bf16_t* p1 = EOT1 + (size_t)row * EC + g;
    bf16x8 s[8];
#pragma unroll
    for (int i = 0; i < 8; ++i) {
        bf16x8 v0 = *(const bf16x8*)(p0 + i * 8);
        bf16x8 v1 = *(const bf16x8*)(p1 + i * 8);
#pragma unroll
        for (int j = 0; j < 8; ++j) s[i][j] = (bf16_t)((float)v0[j] + (float)v1[j]);
    }
    const int key = row & 7;
#pragma unroll
    for (int i = 0; i < 8; ++i)
        *(bf16x8*)(p0 + 8 * (i ^ key)) = s[i];
}

// ============ combine+residual GEMM, 6-way z K-split, atomic blend ============
// z in 0..3: out += w0 * sum_{ec in slice z} cw[s][ec] * EOT[m][ec]
// z in 4..5: out += w1 * (sum_{d in slice}  x[s][d] * RWT[m][d] (+residual_b in z4))
__global__ __launch_bounds__(NT, 4)
void combine_gemm(const float* __restrict__ cw, const bf16_t* __restrict__ EOT,
                  const float* __restrict__ xtail, const bf16_t* __restrict__ RWT,
                  const float* __restrict__ residual_b, const float* __restrict__ rw,
                  float* __restrict__ out)
{
    __shared__ bf16_t As[128 * BK];   // cw or x rows (tokens)
    __shared__ bf16_t Bs[256 * BK];   // EOT or RWT rows (DOUT)
    const int tid = threadIdx.x;

    // T1: bijective XCD-chunked swizzle. nwg = 768 -> 96 ids per XCD.
    int id = blockIdx.x;
    id = (id & 7) * 96 + (id >> 3);
    const int bx = id & 3, by = (id >> 2) & 31, z = id >> 7;

    const int brow = by * 128;   // token
    const int bcol = bx * 256;   // DOUT

    const float* A;
    const bf16_t* B;
    int ld;
    if (z < 4) {
        const int koff = z * 2048;
        A = cw + (size_t)brow * EC + koff;   ld = EC;
        B = EOT + (size_t)bcol * EC + koff;
    } else {
        const int koff = (z - 4) * 2048;
        A = xtail + (size_t)brow * DIN + koff;  ld = DIN;
        B = RWT + (size_t)bcol * DIN + koff;
    }

    const int w = tid >> 6, l = tid & 63;
    const int wr = (w >> 2) * 64, wc = (w & 3) * 64;   // 2x4 waves of 64x64
    const int lr = l & 15, lk = l >> 4, sw = (l & 7) << 3;

    f32x4 acc[4][4] = {};

    for (int k0 = 0; k0 < 2048; k0 += BK) {
        stage_f32<128 * BK>(As, A + k0, ld, tid);
        stage_bf16<256 * BK>(Bs, B + k0, ld, tid);
        __syncthreads();
#pragma unroll
        for (int kk = 0; kk < 2; ++kk) {
            const int cs = (kk * 32 + lk * 8) ^ sw;
            bf16x8 a[4], b[4];
#pragma unroll
            for (int m = 0; m < 4; ++m)
                a[m] = *(const bf16x8*)(&As[(wr + m * 16 + lr) * BK + cs]);
#pragma unroll
            for (int n = 0; n < 4; ++n)
                b[n] = *(const bf16x8*)(&Bs[(wc + n * 16 + lr) * BK + cs]);
#pragma unroll
            for (int m = 0; m < 4; ++m)
#pragma unroll
                for (int n = 0; n < 4; ++n)
                    acc[m][n] = __builtin_amdgcn_mfma_f32_16x16x32_bf16(a[m], b[n], acc[m][n], 0, 0, 0);
        }
        __syncthreads();
    }

#pragma unroll
    for (int m = 0; m < 4; ++m) {
#pragma unroll
        for (int n = 0; n < 4; ++n) {
            const int col = bcol + wc + n * 16 + lr;     // DOUT
#pragma unroll
            for (int j = 0; j < 4; ++j) {
                const int row = brow + wr + m * 16 + lk * 4 + j;   // token
                float v = acc[m][n][j];
                if (z == 4) v += residual_b[col];
                const float scale = rw[2 * row + (z >= 4 ? 1 : 0)];
                atomicAdd(&out[(size_t)row * DOUT + col], scale * v);
            }
        }
    }
}

extern "C" void kernel_launch(void* const* d_in, const int* in_sizes, int n_in,
                              void* d_out, int out_size, void* d_ws, size_t ws_size,
                              hipStream_t stream)
{
    const float* inputs     = (const float*)d_in[0];
    const float* expert_w   = (const float*)d_in[1];
    const float* expert_b   = (const float*)d_in[2];
    const float* residual_w = (const float*)d_in[3];
    const float* residual_b = (const float*)d_in[4];
    const float* combine_w  = (const float*)d_in[5];
    const float* resid_wt   = (const float*)d_in[6];
    float* out = (float*)d_out;
    char* ws = (char*)d_ws;

    bf16_t* WT   = (bf16_t*)(ws + WS_WT);
    bf16_t* RWT  = (bf16_t*)(ws + WS_RWT);
    bf16_t* EOT0 = (bf16_t*)(ws + WS_EOT0);   // becomes merged swizzled EOT
    bf16_t* EOT1 = (bf16_t*)(ws + WS_EOT1);

    // 0) zero the output (blend accumulates atomically)
    hipMemsetAsync(d_out, 0, (size_t)out_size * sizeof(float), stream);

    // 1) weights -> bf16 transposed + swizzled
    transpose_cast_kernel<<<dim3(32, 128, 9), dim3(32, 8), 0, stream>>>(
        expert_w, residual_w, WT, RWT);

    // 2) expert GEMM, split-K x2, 128x256 tiles -> EOT0/EOT1 (plain bf16)
    expert_gemm<<<dim3(512), NT, 0, stream>>>(WT, inputs, EOT0, EOT1, expert_b);

    // 3) merge halves + swizzle in place (EOT0 -> EOT)
    merge_swz_kernel<<<dim3(512), 256, 0, stream>>>(EOT0, EOT1);

    // 4) combine (4 K-slices) + residual (2 K-slices), atomic blend into out
    combine_gemm<<<dim3(768), NT, 0, stream>>>(
        combine_w, EOT0, inputs + (size_t)E_ * C_ * DIN, RWT,
        residual_b, resid_wt, out);
}